// Round 1
// baseline (759.005 us; speedup 1.0000x reference)
//
#include <hip/hip_runtime.h>
#include <hip/hip_bf16.h>
#include <stdint.h>

// Problem: 2-layer GCN on N=100000 nodes, E=3200000 edges, F=128, H=64.
// out = b2 + (1/N) * ( sum_i dinv[i]^2*y[i] + sum_e dinv[row]*dinv[col]*y[row] )
// where y[i] = relu( b1 + dinv[i]*( sum_{e: col=i} dinv[row]*xw[row] + dinv[i]*xw[i] ) ) . W2
// and xw = x @ W1, deg[i] = indeg(i)+1 (self loop), dinv = rsqrt(deg).

#define F_IN 128
#define H_DIM 64

// ---------------- degree count ----------------
__global__ void k_deg(const int* __restrict__ col, int* __restrict__ deg, int E) {
    int e = blockIdx.x * blockDim.x + threadIdx.x;
    if (e < E) atomicAdd(&deg[col[e]], 1);
}

// ---------------- 3-kernel exclusive scan over deg -> offs ----------------
__global__ void k_scan1(const int* __restrict__ deg, int* __restrict__ offs,
                        int* __restrict__ bsum, int N) {
    __shared__ int s[1024];
    int t = threadIdx.x;
    int i = blockIdx.x * 1024 + t;
    int v = (i < N) ? deg[i] : 0;
    s[t] = v;
    __syncthreads();
    for (int d = 1; d < 1024; d <<= 1) {
        int add = (t >= d) ? s[t - d] : 0;
        __syncthreads();
        s[t] += add;
        __syncthreads();
    }
    if (i < N) offs[i] = s[t] - v;       // exclusive
    if (t == 1023) bsum[blockIdx.x] = s[1023];
}

__global__ void k_scan2(int* __restrict__ bsum, int NB) {
    __shared__ int s[1024];
    int t = threadIdx.x;
    int v = (t < NB) ? bsum[t] : 0;
    s[t] = v;
    __syncthreads();
    for (int d = 1; d < 1024; d <<= 1) {
        int add = (t >= d) ? s[t - d] : 0;
        __syncthreads();
        s[t] += add;
        __syncthreads();
    }
    if (t < NB) bsum[t] = s[t] - v;      // exclusive block offsets
}

__global__ void k_scan3(const int* __restrict__ deg, int* __restrict__ offs,
                        const int* __restrict__ bsum, int* __restrict__ cursor,
                        float* __restrict__ dinv, int N, int E) {
    int i = blockIdx.x * 1024 + threadIdx.x;
    if (i < N) {
        int v = offs[i] + bsum[i >> 10];
        offs[i] = v;
        cursor[i] = v;
        dinv[i] = rsqrtf((float)deg[i] + 1.0f);   // +1 self loop
    }
    if (i == 0) offs[N] = E;
}

// ---------------- CSR fill (order within segment arbitrary) ----------------
__global__ void k_fill(const int* __restrict__ row, const int* __restrict__ col,
                       int* __restrict__ cursor, int* __restrict__ csr, int E) {
    int e = blockIdx.x * blockDim.x + threadIdx.x;
    if (e < E) {
        int c = col[e];
        int p = atomicAdd(&cursor[c], 1);
        csr[p] = row[e];
    }
}

// ---------------- xw = x @ W1 : tiled 64x64, K=128 ----------------
__global__ __launch_bounds__(256) void k_gemm1(const float* __restrict__ x,
                                               const float* __restrict__ W1,
                                               float* __restrict__ xw, int N) {
    __shared__ float xs[64 * 132];   // pad 128->132 to break bank conflicts
    __shared__ float ws[128 * 64];
    int tid = threadIdx.x;
    int row0 = blockIdx.x * 64;

    // load W1 (8192 floats = 2048 float4) -> 8 float4/thread
    const float4* w4 = (const float4*)W1;
    float4* ws4 = (float4*)ws;
#pragma unroll
    for (int i = 0; i < 8; i++) ws4[tid + 256 * i] = w4[tid + 256 * i];

    // load x tile 64x128 (2048 float4) -> 8 float4/thread
#pragma unroll
    for (int i = 0; i < 8; i++) {
        int idx = tid + 256 * i;      // float4 index in tile
        int r = idx >> 5;             // 32 float4 per row
        int c = idx & 31;
        float4 v = make_float4(0.f, 0.f, 0.f, 0.f);
        int gr = row0 + r;
        if (gr < N) v = ((const float4*)x)[(size_t)gr * 32 + c];
        *(float4*)&xs[r * 132 + c * 4] = v;   // 528B row stride, 16B aligned
    }
    __syncthreads();

    int tx = tid & 15, ty = tid >> 4;
    float acc[4][4] = {};
#pragma unroll 4
    for (int k = 0; k < 128; k++) {
        float4 wv = *(const float4*)&ws[k * 64 + tx * 4];
#pragma unroll
        for (int i = 0; i < 4; i++) {
            float xv = xs[(ty * 4 + i) * 132 + k];
            acc[i][0] += xv * wv.x;
            acc[i][1] += xv * wv.y;
            acc[i][2] += xv * wv.z;
            acc[i][3] += xv * wv.w;
        }
    }
#pragma unroll
    for (int i = 0; i < 4; i++) {
        int gr = row0 + ty * 4 + i;
        if (gr < N) {
            float4 o = make_float4(acc[i][0], acc[i][1], acc[i][2], acc[i][3]);
            ((float4*)&xw[(size_t)gr * 64])[tx] = o;
        }
    }
}

// ---------------- layer-1 aggregation fused with relu + dot(W2) ----------------
// one wave per node, lane = feature
__global__ __launch_bounds__(256) void k_agg(const float* __restrict__ xw,
                                             const int* __restrict__ csr,
                                             const int* __restrict__ offs,
                                             const float* __restrict__ dinv,
                                             const float* __restrict__ b1,
                                             const float* __restrict__ W2,
                                             float* __restrict__ y, int N) {
    int wid = (blockIdx.x * blockDim.x + threadIdx.x) >> 6;
    int lane = threadIdx.x & 63;
    if (wid >= N) return;
    int i = wid;
    float di = dinv[i];
    float acc = di * xw[(size_t)i * H_DIM + lane];   // self loop term
    int p = offs[i], pe = offs[i + 1];
    for (; p < pe; p++) {
        int j = csr[p];
        acc += dinv[j] * xw[(size_t)j * H_DIM + lane];
    }
    float h = b1[lane] + di * acc;
    h = fmaxf(h, 0.f);
    float v = h * W2[lane];
#pragma unroll
    for (int d = 32; d > 0; d >>= 1) v += __shfl_xor(v, d, 64);
    if (lane == 0) y[i] = v;
}

// ---------------- final fused layer-2 + mean reduction ----------------
__global__ __launch_bounds__(256) void k_final(const int* __restrict__ row,
                                               const int* __restrict__ col,
                                               const float* __restrict__ dinv,
                                               const float* __restrict__ y,
                                               double* __restrict__ acc,
                                               int N, int E) {
    int tid = blockIdx.x * blockDim.x + threadIdx.x;
    int stride = gridDim.x * blockDim.x;
    float local = 0.f;
    for (int e = tid; e < E; e += stride) {
        int r = row[e];
        local += dinv[r] * dinv[col[e]] * y[r];
    }
    for (int i = tid; i < N; i += stride) {
        float d = dinv[i];
        local += d * d * y[i];
    }
#pragma unroll
    for (int d = 32; d > 0; d >>= 1) local += __shfl_xor(local, d, 64);
    __shared__ float wsum[4];
    int lane = threadIdx.x & 63, w = threadIdx.x >> 6;
    if (lane == 0) wsum[w] = local;
    __syncthreads();
    if (threadIdx.x == 0) {
        float s = wsum[0] + wsum[1] + wsum[2] + wsum[3];
        atomicAdd(acc, (double)s);
    }
}

__global__ void k_write(const double* __restrict__ acc, const float* __restrict__ b2,
                        float* __restrict__ out, int N) {
    out[0] = b2[0] + (float)(acc[0] / (double)N);
}

extern "C" void kernel_launch(void* const* d_in, const int* in_sizes, int n_in,
                              void* d_out, int out_size, void* d_ws, size_t ws_size,
                              hipStream_t stream) {
    const float* x  = (const float*)d_in[0];
    const int*   ei = (const int*)d_in[1];
    const float* W1 = (const float*)d_in[2];
    const float* b1 = (const float*)d_in[3];
    const float* W2 = (const float*)d_in[4];
    const float* b2 = (const float*)d_in[5];

    int N = in_sizes[0] / F_IN;
    int E = in_sizes[1] / 2;
    const int* erow = ei;        // edge_index[0] = sources
    const int* ecol = ei + E;    // edge_index[1] = targets

    // workspace layout
    char* w = (char*)d_ws;
    auto take = [&](size_t bytes) {
        char* p = w;
        w += (bytes + 255) & ~(size_t)255;
        return p;
    };
    int*    deg    = (int*)take((size_t)N * 4);
    double* acc    = (double*)take(16);
    int*    offs   = (int*)take((size_t)(N + 1) * 4);
    int*    cursor = (int*)take((size_t)N * 4);
    float*  dinv   = (float*)take((size_t)N * 4);
    float*  y      = (float*)take((size_t)N * 4);
    int*    bsum   = (int*)take(1024 * 4);
    int*    csr    = (int*)take((size_t)E * 4);
    float*  xw     = (float*)take((size_t)N * H_DIM * 4);
    (void)ws_size;

    float* out = (float*)d_out;

    // zero the atomically-accumulated buffers (ws is poisoned, not re-zeroed)
    hipMemsetAsync(deg, 0, (size_t)N * 4, stream);
    hipMemsetAsync(acc, 0, 16, stream);

    int eb = (E + 255) / 256;
    k_deg<<<eb, 256, 0, stream>>>(ecol, deg, E);

    int NB = (N + 1023) / 1024;
    k_scan1<<<NB, 1024, 0, stream>>>(deg, offs, bsum, N);
    k_scan2<<<1, 1024, 0, stream>>>(bsum, NB);
    k_scan3<<<NB, 1024, 0, stream>>>(deg, offs, bsum, cursor, dinv, N, E);

    k_fill<<<eb, 256, 0, stream>>>(erow, ecol, cursor, csr, E);

    k_gemm1<<<(N + 63) / 64, 256, 0, stream>>>(x, W1, xw, N);

    k_agg<<<((size_t)N * 64 + 255) / 256, 256, 0, stream>>>(xw, csr, offs, dinv, b1, W2, y, N);

    k_final<<<1024, 256, 0, stream>>>(erow, ecol, dinv, y, acc, N, E);

    k_write<<<1, 1, 0, stream>>>(acc, b2, out, N);
}

// Round 2
// 395.780 us; speedup vs baseline: 1.9177x; 1.9177x over previous
//
#include <hip/hip_runtime.h>
#include <hip/hip_bf16.h>
#include <stdint.h>

// 2-layer GCN, N=100000, E=3200000, F=128, H=64.
// out = b2 + (1/N)*( sum_i dinv[i]*yp[i] + sum_e yp[row]*dinv[col] )
// yp[i] = dinv[i]*relu(b1 + dinv[i]*(sum_{e:col=i} xws[row] + xws[i])).W2
// xws[j] = dinv[j]*(x@W1)[j]  stored bf16;  deg[i]=indeg+1, dinv=rsqrt(deg).

#define F_IN 128
#define H_DIM 64

typedef int   i4 __attribute__((ext_vector_type(4)));
typedef float f4 __attribute__((ext_vector_type(4)));

__device__ __forceinline__ float bf2f(ushort u) {
    return __uint_as_float(((unsigned int)u) << 16);
}

// ---------------- degree count + per-edge rank ----------------
__global__ __launch_bounds__(256) void k_deg(const int* __restrict__ col,
                                             int* __restrict__ deg,
                                             int* __restrict__ rank, int E) {
    int t = blockIdx.x * blockDim.x + threadIdx.x;
    int E4 = E >> 2;
    if (t < E4) {
        i4 c = __builtin_nontemporal_load((const i4*)col + t);
        i4 r;
        r.x = atomicAdd(&deg[c.x], 1);
        r.y = atomicAdd(&deg[c.y], 1);
        r.z = atomicAdd(&deg[c.z], 1);
        r.w = atomicAdd(&deg[c.w], 1);
        __builtin_nontemporal_store(r, (i4*)rank + t);
    } else {
        int e = (E4 << 2) + (t - E4);
        if (e < E) rank[e] = atomicAdd(&deg[col[e]], 1);
    }
}

// ---------------- 3-kernel exclusive scan over deg -> offs ----------------
__global__ void k_scan1(const int* __restrict__ deg, int* __restrict__ offs,
                        int* __restrict__ bsum, int N) {
    __shared__ int s[1024];
    int t = threadIdx.x;
    int i = blockIdx.x * 1024 + t;
    int v = (i < N) ? deg[i] : 0;
    s[t] = v;
    __syncthreads();
    for (int d = 1; d < 1024; d <<= 1) {
        int add = (t >= d) ? s[t - d] : 0;
        __syncthreads();
        s[t] += add;
        __syncthreads();
    }
    if (i < N) offs[i] = s[t] - v;
    if (t == 1023) bsum[blockIdx.x] = s[1023];
}

__global__ void k_scan2(int* __restrict__ bsum, int NB) {
    __shared__ int s[1024];
    int t = threadIdx.x;
    int v = (t < NB) ? bsum[t] : 0;
    s[t] = v;
    __syncthreads();
    for (int d = 1; d < 1024; d <<= 1) {
        int add = (t >= d) ? s[t - d] : 0;
        __syncthreads();
        s[t] += add;
        __syncthreads();
    }
    if (t < NB) bsum[t] = s[t] - v;
}

__global__ void k_scan3(const int* __restrict__ deg, int* __restrict__ offs,
                        const int* __restrict__ bsum, float* __restrict__ dinv,
                        int N, int E) {
    int i = blockIdx.x * 1024 + threadIdx.x;
    if (i < N) {
        offs[i] += bsum[i >> 10];
        dinv[i] = rsqrtf((float)deg[i] + 1.0f);   // +1 self loop
    }
    if (i == 0) offs[N] = E;
}

// ---------------- CSR fill, atomic-free ----------------
__global__ __launch_bounds__(256) void k_fill(const int* __restrict__ row,
                                              const int* __restrict__ col,
                                              const int* __restrict__ rank,
                                              const int* __restrict__ offs,
                                              int* __restrict__ csr, int E) {
    int t = blockIdx.x * blockDim.x + threadIdx.x;
    int E4 = E >> 2;
    if (t < E4) {
        i4 c = __builtin_nontemporal_load((const i4*)col + t);
        i4 r = __builtin_nontemporal_load((const i4*)row + t);
        i4 k = __builtin_nontemporal_load((const i4*)rank + t);
        csr[offs[c.x] + k.x] = r.x;
        csr[offs[c.y] + k.y] = r.y;
        csr[offs[c.z] + k.z] = r.z;
        csr[offs[c.w] + k.w] = r.w;
    } else {
        int e = (E4 << 2) + (t - E4);
        if (e < E) csr[offs[col[e]] + rank[e]] = row[e];
    }
}

// ---------------- xws = dinv * (x @ W1), bf16 out ----------------
__global__ __launch_bounds__(256) void k_gemm1(const float* __restrict__ x,
                                               const float* __restrict__ W1,
                                               const float* __restrict__ dinv,
                                               ushort* __restrict__ xwb, int N) {
    __shared__ float xs[64 * 132];
    __shared__ float ws[128 * 64];
    int tid = threadIdx.x;
    int row0 = blockIdx.x * 64;

    const float4* w4 = (const float4*)W1;
    float4* ws4 = (float4*)ws;
#pragma unroll
    for (int i = 0; i < 8; i++) ws4[tid + 256 * i] = w4[tid + 256 * i];

#pragma unroll
    for (int i = 0; i < 8; i++) {
        int idx = tid + 256 * i;
        int r = idx >> 5;
        int c = idx & 31;
        f4 v = {0.f, 0.f, 0.f, 0.f};
        int gr = row0 + r;
        if (gr < N) v = __builtin_nontemporal_load((const f4*)x + (size_t)gr * 32 + c);
        *(f4*)&xs[r * 132 + c * 4] = v;
    }
    __syncthreads();

    int tx = tid & 15, ty = tid >> 4;
    float acc[4][4] = {};
#pragma unroll 4
    for (int k = 0; k < 128; k++) {
        float4 wv = *(const float4*)&ws[k * 64 + tx * 4];
#pragma unroll
        for (int i = 0; i < 4; i++) {
            float xv = xs[(ty * 4 + i) * 132 + k];
            acc[i][0] += xv * wv.x;
            acc[i][1] += xv * wv.y;
            acc[i][2] += xv * wv.z;
            acc[i][3] += xv * wv.w;
        }
    }
#pragma unroll
    for (int i = 0; i < 4; i++) {
        int gr = row0 + ty * 4 + i;
        if (gr < N) {
            float dsc = dinv[gr];
            __hip_bfloat16 b0 = __float2bfloat16(acc[i][0] * dsc);
            __hip_bfloat16 b1 = __float2bfloat16(acc[i][1] * dsc);
            __hip_bfloat16 b2 = __float2bfloat16(acc[i][2] * dsc);
            __hip_bfloat16 b3 = __float2bfloat16(acc[i][3] * dsc);
            ushort4 o = make_ushort4(*(ushort*)&b0, *(ushort*)&b1,
                                     *(ushort*)&b2, *(ushort*)&b3);
            *(ushort4*)&xwb[(size_t)gr * 64 + tx * 4] = o;
        }
    }
}

// ---------------- layer-1 aggregation + relu + dot(W2), one wave/node ----------------
__global__ __launch_bounds__(256) void k_agg(const ushort* __restrict__ xws,
                                             const int* __restrict__ csr,
                                             const int* __restrict__ offs,
                                             const float* __restrict__ dinv,
                                             const float* __restrict__ b1,
                                             const float* __restrict__ W2,
                                             float* __restrict__ yp, int N) {
    int wid = (blockIdx.x * blockDim.x + threadIdx.x) >> 6;
    int lane = threadIdx.x & 63;
    if (wid >= N) return;
    float di = dinv[wid];
    float acc = bf2f(xws[(size_t)wid * H_DIM + lane]);   // self loop (pre-scaled)
    int p = offs[wid], pe = offs[wid + 1];
    for (; p + 8 <= pe; p += 8) {
        int j0 = csr[p + 0], j1 = csr[p + 1], j2 = csr[p + 2], j3 = csr[p + 3];
        int j4 = csr[p + 4], j5 = csr[p + 5], j6 = csr[p + 6], j7 = csr[p + 7];
        float v0 = bf2f(xws[(size_t)j0 * H_DIM + lane]);
        float v1 = bf2f(xws[(size_t)j1 * H_DIM + lane]);
        float v2 = bf2f(xws[(size_t)j2 * H_DIM + lane]);
        float v3 = bf2f(xws[(size_t)j3 * H_DIM + lane]);
        float v4 = bf2f(xws[(size_t)j4 * H_DIM + lane]);
        float v5 = bf2f(xws[(size_t)j5 * H_DIM + lane]);
        float v6 = bf2f(xws[(size_t)j6 * H_DIM + lane]);
        float v7 = bf2f(xws[(size_t)j7 * H_DIM + lane]);
        acc += ((v0 + v1) + (v2 + v3)) + ((v4 + v5) + (v6 + v7));
    }
    for (; p < pe; p++)
        acc += bf2f(xws[(size_t)csr[p] * H_DIM + lane]);
    float h = fmaxf(b1[lane] + di * acc, 0.f);
    float v = h * W2[lane];
#pragma unroll
    for (int d = 32; d > 0; d >>= 1) v += __shfl_xor(v, d, 64);
    if (lane == 0) yp[wid] = di * v;
}

// ---------------- final fused layer-2 + mean reduction ----------------
__global__ __launch_bounds__(256) void k_final(const int* __restrict__ row,
                                               const int* __restrict__ col,
                                               const float* __restrict__ dinv,
                                               const float* __restrict__ yp,
                                               double* __restrict__ acc,
                                               int N, int E) {
    int tid = blockIdx.x * blockDim.x + threadIdx.x;
    int nthr = gridDim.x * blockDim.x;
    float local = 0.f;
    int E4 = E >> 2;
    for (int t = tid; t < E4; t += nthr) {
        i4 r = __builtin_nontemporal_load((const i4*)row + t);
        i4 c = __builtin_nontemporal_load((const i4*)col + t);
        local += yp[r.x] * dinv[c.x] + yp[r.y] * dinv[c.y]
               + yp[r.z] * dinv[c.z] + yp[r.w] * dinv[c.w];
    }
    for (int e = (E4 << 2) + tid; e < E; e += nthr)
        local += yp[row[e]] * dinv[col[e]];
    int N4 = N >> 2;
    for (int t = tid; t < N4; t += nthr) {
        f4 d = *((const f4*)dinv + t);
        f4 yv = *((const f4*)yp + t);
        local += d.x * yv.x + d.y * yv.y + d.z * yv.z + d.w * yv.w;
    }
    for (int i = (N4 << 2) + tid; i < N; i += nthr)
        local += dinv[i] * yp[i];
#pragma unroll
    for (int d = 32; d > 0; d >>= 1) local += __shfl_xor(local, d, 64);
    __shared__ float wsum[4];
    int lane = threadIdx.x & 63, w = threadIdx.x >> 6;
    if (lane == 0) wsum[w] = local;
    __syncthreads();
    if (threadIdx.x == 0) {
        float s = wsum[0] + wsum[1] + wsum[2] + wsum[3];
        atomicAdd(acc, (double)s);
    }
}

__global__ void k_write(const double* __restrict__ acc, const float* __restrict__ b2,
                        float* __restrict__ out, int N) {
    out[0] = b2[0] + (float)(acc[0] / (double)N);
}

extern "C" void kernel_launch(void* const* d_in, const int* in_sizes, int n_in,
                              void* d_out, int out_size, void* d_ws, size_t ws_size,
                              hipStream_t stream) {
    const float* x  = (const float*)d_in[0];
    const int*   ei = (const int*)d_in[1];
    const float* W1 = (const float*)d_in[2];
    const float* b1 = (const float*)d_in[3];
    const float* W2 = (const float*)d_in[4];
    const float* b2 = (const float*)d_in[5];

    int N = in_sizes[0] / F_IN;
    int E = in_sizes[1] / 2;
    const int* erow = ei;        // sources
    const int* ecol = ei + E;    // targets

    char* w = (char*)d_ws;
    auto take = [&](size_t bytes) {
        char* p = w;
        w += (bytes + 255) & ~(size_t)255;
        return p;
    };
    int*    deg  = (int*)take((size_t)N * 4);
    double* acc  = (double*)take(16);
    int*    offs = (int*)take((size_t)(N + 1) * 4);
    float*  dinv = (float*)take((size_t)N * 4);
    float*  yp   = (float*)take((size_t)N * 4);
    int*    bsum = (int*)take(1024 * 4);
    int*    rank = (int*)take((size_t)E * 4);
    int*    csr  = (int*)take((size_t)E * 4);
    ushort* xwb  = (ushort*)take((size_t)N * H_DIM * 2);
    (void)ws_size;

    float* out = (float*)d_out;

    hipMemsetAsync(deg, 0, (size_t)N * 4, stream);
    hipMemsetAsync(acc, 0, 16, stream);

    int E4 = E >> 2;
    int degThreads = E4 + 4;
    int eb4 = (degThreads + 255) / 256;
    k_deg<<<eb4, 256, 0, stream>>>(ecol, deg, rank, E);

    int NB = (N + 1023) / 1024;
    k_scan1<<<NB, 1024, 0, stream>>>(deg, offs, bsum, N);
    k_scan2<<<1, 1024, 0, stream>>>(bsum, NB);
    k_scan3<<<NB, 1024, 0, stream>>>(deg, offs, bsum, dinv, N, E);

    k_fill<<<eb4, 256, 0, stream>>>(erow, ecol, rank, offs, csr, E);

    k_gemm1<<<(N + 63) / 64, 256, 0, stream>>>(x, W1, dinv, xwb, N);

    k_agg<<<((size_t)N * 64 + 255) / 256, 256, 0, stream>>>(xwb, csr, offs, dinv, b1, W2, yp, N);

    k_final<<<1024, 256, 0, stream>>>(erow, ecol, dinv, yp, acc, N, E);

    k_write<<<1, 1, 0, stream>>>(acc, b2, out, N);
}

// Round 3
// 381.213 us; speedup vs baseline: 1.9910x; 1.0382x over previous
//
#include <hip/hip_runtime.h>
#include <hip/hip_bf16.h>
#include <stdint.h>

// 2-layer GCN, N=100000, E=3200000, F=128, H=64.
// out = b2 + (1/N)*( sum_i dinv[i]*yp[i] + sum_e yp[row]*dinv[col] )
// yp[i] = dinv[i]*relu(b1 + dinv[i]*(sum_{e:col=i} xws[row] + xws[i])).W2
// xws[j] = dinv[j]*(x@W1)[j]  stored bf16;  deg[i]=indeg+1, dinv=rsqrt(deg).
// deg histogram is replicated 8x (replica = blockIdx&7 ~ XCD id) so atomics
// stay within one XCD's L2 instead of ping-ponging lines across XCDs.

#define F_IN 128
#define H_DIM 64
#define NREP 8

typedef int   i4 __attribute__((ext_vector_type(4)));
typedef float f4 __attribute__((ext_vector_type(4)));

__device__ __forceinline__ float bf2f(ushort u) {
    return __uint_as_float(((unsigned int)u) << 16);
}
// ushort2-as-uint -> two floats (low half = even feature)
__device__ __forceinline__ float2 bfp(unsigned int u) {
    return make_float2(__uint_as_float(u << 16), __uint_as_float(u & 0xffff0000u));
}

// ---------------- degree count (replicated) + per-edge replica-local rank ----------------
__global__ __launch_bounds__(256) void k_deg(const int* __restrict__ col,
                                             int* __restrict__ deg_r,
                                             int* __restrict__ rank, int E, int N) {
    int t = blockIdx.x * blockDim.x + threadIdx.x;
    int* deg = deg_r + (size_t)(blockIdx.x & (NREP - 1)) * N;
    int E4 = E >> 2;
    if (t < E4) {
        i4 c = __builtin_nontemporal_load((const i4*)col + t);
        i4 r;
        r.x = atomicAdd(&deg[c.x], 1);
        r.y = atomicAdd(&deg[c.y], 1);
        r.z = atomicAdd(&deg[c.z], 1);
        r.w = atomicAdd(&deg[c.w], 1);
        __builtin_nontemporal_store(r, (i4*)rank + t);
    } else {
        int e = (E4 << 2) + (t - E4);
        if (e < E) rank[e] = atomicAdd(&deg[col[e]], 1);
    }
}

// ---------------- scan: offs = excl-prefix of total deg; replica bases ----------------
__global__ void k_scan1(const int* __restrict__ deg_r, int* __restrict__ offs,
                        int* __restrict__ bsum, int N) {
    __shared__ int s[1024];
    int t = threadIdx.x;
    int i = blockIdx.x * 1024 + t;
    int v = 0;
    if (i < N) {
#pragma unroll
        for (int r = 0; r < NREP; r++) v += deg_r[(size_t)r * N + i];
    }
    s[t] = v;
    __syncthreads();
    for (int d = 1; d < 1024; d <<= 1) {
        int add = (t >= d) ? s[t - d] : 0;
        __syncthreads();
        s[t] += add;
        __syncthreads();
    }
    if (i < N) offs[i] = s[t] - v;
    if (t == 1023) bsum[blockIdx.x] = s[1023];
}

__global__ void k_scan2(int* __restrict__ bsum, int NB) {
    __shared__ int s[1024];
    int t = threadIdx.x;
    int v = (t < NB) ? bsum[t] : 0;
    s[t] = v;
    __syncthreads();
    for (int d = 1; d < 1024; d <<= 1) {
        int add = (t >= d) ? s[t - d] : 0;
        __syncthreads();
        s[t] += add;
        __syncthreads();
    }
    if (t < NB) bsum[t] = s[t] - v;
}

// convert deg_r counts -> absolute base positions (offs folded in); offs, dinv
__global__ void k_scan3(int* __restrict__ deg_r, int* __restrict__ offs,
                        const int* __restrict__ bsum, float* __restrict__ dinv,
                        int N, int E) {
    int i = blockIdx.x * 1024 + threadIdx.x;
    if (i < N) {
        int o = offs[i] + bsum[i >> 10];
        offs[i] = o;
        int running = o;
#pragma unroll
        for (int r = 0; r < NREP; r++) {
            int c = deg_r[(size_t)r * N + i];
            deg_r[(size_t)r * N + i] = running;
            running += c;
        }
        dinv[i] = rsqrtf((float)(running - o) + 1.0f);   // +1 self loop
    }
    if (i == 0) offs[N] = E;
}

// ---------------- CSR fill, atomic-free ----------------
__global__ __launch_bounds__(256) void k_fill(const int* __restrict__ row,
                                              const int* __restrict__ col,
                                              const int* __restrict__ rank,
                                              const int* __restrict__ base_r,
                                              int* __restrict__ csr, int E, int N) {
    int t = blockIdx.x * blockDim.x + threadIdx.x;
    const int* base = base_r + (size_t)(blockIdx.x & (NREP - 1)) * N;
    int E4 = E >> 2;
    if (t < E4) {
        i4 c = __builtin_nontemporal_load((const i4*)col + t);
        i4 r = __builtin_nontemporal_load((const i4*)row + t);
        i4 k = __builtin_nontemporal_load((const i4*)rank + t);
        csr[base[c.x] + k.x] = r.x;
        csr[base[c.y] + k.y] = r.y;
        csr[base[c.z] + k.z] = r.z;
        csr[base[c.w] + k.w] = r.w;
    } else {
        int e = (E4 << 2) + (t - E4);
        if (e < E) csr[base[col[e]] + rank[e]] = row[e];
    }
}

// ---------------- xws = dinv * (x @ W1), bf16 out ----------------
__global__ __launch_bounds__(256) void k_gemm1(const float* __restrict__ x,
                                               const float* __restrict__ W1,
                                               const float* __restrict__ dinv,
                                               ushort* __restrict__ xwb, int N) {
    __shared__ float xs[64 * 132];
    __shared__ float ws[128 * 64];
    int tid = threadIdx.x;
    int row0 = blockIdx.x * 64;

    const float4* w4 = (const float4*)W1;
    float4* ws4 = (float4*)ws;
#pragma unroll
    for (int i = 0; i < 8; i++) ws4[tid + 256 * i] = w4[tid + 256 * i];

#pragma unroll
    for (int i = 0; i < 8; i++) {
        int idx = tid + 256 * i;
        int r = idx >> 5;
        int c = idx & 31;
        f4 v = {0.f, 0.f, 0.f, 0.f};
        int gr = row0 + r;
        if (gr < N) v = __builtin_nontemporal_load((const f4*)x + (size_t)gr * 32 + c);
        *(f4*)&xs[r * 132 + c * 4] = v;
    }
    __syncthreads();

    int tx = tid & 15, ty = tid >> 4;
    float acc[4][4] = {};
#pragma unroll 4
    for (int k = 0; k < 128; k++) {
        float4 wv = *(const float4*)&ws[k * 64 + tx * 4];
#pragma unroll
        for (int i = 0; i < 4; i++) {
            float xv = xs[(ty * 4 + i) * 132 + k];
            acc[i][0] += xv * wv.x;
            acc[i][1] += xv * wv.y;
            acc[i][2] += xv * wv.z;
            acc[i][3] += xv * wv.w;
        }
    }
#pragma unroll
    for (int i = 0; i < 4; i++) {
        int gr = row0 + ty * 4 + i;
        if (gr < N) {
            float dsc = dinv[gr];
            __hip_bfloat16 b0 = __float2bfloat16(acc[i][0] * dsc);
            __hip_bfloat16 b1 = __float2bfloat16(acc[i][1] * dsc);
            __hip_bfloat16 b2 = __float2bfloat16(acc[i][2] * dsc);
            __hip_bfloat16 b3 = __float2bfloat16(acc[i][3] * dsc);
            ushort4 o = make_ushort4(*(ushort*)&b0, *(ushort*)&b1,
                                     *(ushort*)&b2, *(ushort*)&b3);
            *(ushort4*)&xwb[(size_t)gr * 64 + tx * 4] = o;
        }
    }
}

// ---------------- layer-1 aggregation + relu + dot(W2) ----------------
// one wave per node; lane=(half,m): feature pair (2m,2m+1), halves take
// alternate edges -> one ushort2 gather instruction covers 2 neighbor rows.
__global__ __launch_bounds__(256) void k_agg(const ushort* __restrict__ xws,
                                             const int* __restrict__ csr,
                                             const int* __restrict__ offs,
                                             const float* __restrict__ dinv,
                                             const float* __restrict__ b1,
                                             const float* __restrict__ W2,
                                             float* __restrict__ yp, int N) {
    int wid = (blockIdx.x * blockDim.x + threadIdx.x) >> 6;
    int lane = threadIdx.x & 63;
    if (wid >= N) return;
    int m = lane & 31, half = lane >> 5;
    const unsigned int* xw2 = (const unsigned int*)xws;   // ushort2 view

    float di = dinv[wid];
    float2 bv = ((const float2*)b1)[m];
    float2 wv = ((const float2*)W2)[m];

    float a0 = 0.f, a1 = 0.f;
    if (half == 0) {          // self loop counted once
        float2 s = bfp(xw2[(size_t)wid * 32 + m]);
        a0 += s.x; a1 += s.y;
    }
    int p = offs[wid], pe = offs[wid + 1];
    for (; p + 8 <= pe; p += 8) {
        int j0 = csr[p + 0 + half];
        int j1 = csr[p + 2 + half];
        int j2 = csr[p + 4 + half];
        int j3 = csr[p + 6 + half];
        float2 v0 = bfp(xw2[(size_t)j0 * 32 + m]);
        float2 v1 = bfp(xw2[(size_t)j1 * 32 + m]);
        float2 v2 = bfp(xw2[(size_t)j2 * 32 + m]);
        float2 v3 = bfp(xw2[(size_t)j3 * 32 + m]);
        a0 += (v0.x + v1.x) + (v2.x + v3.x);
        a1 += (v0.y + v1.y) + (v2.y + v3.y);
    }
    for (; p + 2 <= pe; p += 2) {
        int j = csr[p + half];
        float2 v = bfp(xw2[(size_t)j * 32 + m]);
        a0 += v.x; a1 += v.y;
    }
    if (p < pe && half == 0) {     // odd tail edge
        int j = csr[p];
        float2 v = bfp(xw2[(size_t)j * 32 + m]);
        a0 += v.x; a1 += v.y;
    }
    // combine halves (same feature pair in both halves)
    a0 += __shfl_xor(a0, 32, 64);
    a1 += __shfl_xor(a1, 32, 64);
    float h0 = fmaxf(bv.x + di * a0, 0.f);
    float h1 = fmaxf(bv.y + di * a1, 0.f);
    float v = h0 * wv.x + h1 * wv.y;
#pragma unroll
    for (int d = 16; d > 0; d >>= 1) v += __shfl_xor(v, d, 64);
    if (lane == 0) yp[wid] = di * v;
}

// ---------------- final fused layer-2 + mean reduction ----------------
__global__ __launch_bounds__(256) void k_final(const int* __restrict__ row,
                                               const int* __restrict__ col,
                                               const float* __restrict__ dinv,
                                               const float* __restrict__ yp,
                                               double* __restrict__ acc,
                                               int N, int E) {
    int tid = blockIdx.x * blockDim.x + threadIdx.x;
    int nthr = gridDim.x * blockDim.x;
    float local = 0.f;
    int E4 = E >> 2;
    for (int t = tid; t < E4; t += nthr) {
        i4 r = __builtin_nontemporal_load((const i4*)row + t);
        i4 c = __builtin_nontemporal_load((const i4*)col + t);
        local += yp[r.x] * dinv[c.x] + yp[r.y] * dinv[c.y]
               + yp[r.z] * dinv[c.z] + yp[r.w] * dinv[c.w];
    }
    for (int e = (E4 << 2) + tid; e < E; e += nthr)
        local += yp[row[e]] * dinv[col[e]];
    int N4 = N >> 2;
    for (int t = tid; t < N4; t += nthr) {
        f4 d = *((const f4*)dinv + t);
        f4 yv = *((const f4*)yp + t);
        local += d.x * yv.x + d.y * yv.y + d.z * yv.z + d.w * yv.w;
    }
    for (int i = (N4 << 2) + tid; i < N; i += nthr)
        local += dinv[i] * yp[i];
#pragma unroll
    for (int d = 32; d > 0; d >>= 1) local += __shfl_xor(local, d, 64);
    __shared__ float wsum[4];
    int lane = threadIdx.x & 63, w = threadIdx.x >> 6;
    if (lane == 0) wsum[w] = local;
    __syncthreads();
    if (threadIdx.x == 0) {
        float s = wsum[0] + wsum[1] + wsum[2] + wsum[3];
        atomicAdd(acc, (double)s);
    }
}

__global__ void k_write(const double* __restrict__ acc, const float* __restrict__ b2,
                        float* __restrict__ out, int N) {
    out[0] = b2[0] + (float)(acc[0] / (double)N);
}

extern "C" void kernel_launch(void* const* d_in, const int* in_sizes, int n_in,
                              void* d_out, int out_size, void* d_ws, size_t ws_size,
                              hipStream_t stream) {
    const float* x  = (const float*)d_in[0];
    const int*   ei = (const int*)d_in[1];
    const float* W1 = (const float*)d_in[2];
    const float* b1 = (const float*)d_in[3];
    const float* W2 = (const float*)d_in[4];
    const float* b2 = (const float*)d_in[5];

    int N = in_sizes[0] / F_IN;
    int E = in_sizes[1] / 2;
    const int* erow = ei;        // sources
    const int* ecol = ei + E;    // targets

    char* w = (char*)d_ws;
    auto take = [&](size_t bytes) {
        char* p = w;
        w += (bytes + 255) & ~(size_t)255;
        return p;
    };
    int*    deg_r = (int*)take((size_t)NREP * N * 4);
    double* acc   = (double*)take(16);
    int*    offs  = (int*)take((size_t)(N + 1) * 4);
    float*  dinv  = (float*)take((size_t)N * 4);
    float*  yp    = (float*)take((size_t)N * 4);
    int*    bsum  = (int*)take(1024 * 4);
    int*    rank  = (int*)take((size_t)E * 4);
    int*    csr   = (int*)take((size_t)E * 4);
    ushort* xwb   = (ushort*)take((size_t)N * H_DIM * 2);
    (void)ws_size;

    float* out = (float*)d_out;

    hipMemsetAsync(deg_r, 0, (size_t)NREP * N * 4, stream);
    hipMemsetAsync(acc, 0, 16, stream);

    int E4 = E >> 2;
    int degThreads = E4 + 4;
    int eb4 = (degThreads + 255) / 256;
    k_deg<<<eb4, 256, 0, stream>>>(ecol, deg_r, rank, E, N);

    int NB = (N + 1023) / 1024;
    k_scan1<<<NB, 1024, 0, stream>>>(deg_r, offs, bsum, N);
    k_scan2<<<1, 1024, 0, stream>>>(bsum, NB);
    k_scan3<<<NB, 1024, 0, stream>>>(deg_r, offs, bsum, dinv, N, E);

    k_fill<<<eb4, 256, 0, stream>>>(erow, ecol, rank, deg_r, csr, E, N);

    k_gemm1<<<(N + 63) / 64, 256, 0, stream>>>(x, W1, dinv, xwb, N);

    k_agg<<<((size_t)N * 64 + 255) / 256, 256, 0, stream>>>(xwb, csr, offs, dinv, b1, W2, yp, N);

    k_final<<<1024, 256, 0, stream>>>(erow, ecol, dinv, yp, acc, N, E);

    k_write<<<1, 1, 0, stream>>>(acc, b2, out, N);
}